// Round 2
// baseline (73.368 us; speedup 1.0000x reference)
//
#include <hip/hip_runtime.h>
#include <math.h>

#define N_WAVES 128
#define BLOCK 256
#define PPT 4   // points per thread

// out[n] = sum_w c0*sin(2pi*f*(x0*cos r + x1*sin r)) + c1*cos(...)
//        = sum_w R_w * sin(2pi*(a_w*x0 + b_w*x1) + phi_w)
// a = f*cos r, b = f*sin r, R = hypot(c0,c1), phi = atan2(c1,c0).
// v_sin_f32 computes sin(2pi*x), x in revolutions -> keep phase in revs,
// range-reduce with v_fract_f32.

// One-block setup: all transcendental/libm wave-param math done ONCE,
// not per-block in the hot kernel.
__global__ void setup_kernel(const float* __restrict__ freqs,
                             const float* __restrict__ rots,
                             const float* __restrict__ coeffs,
                             float4* __restrict__ wp_out) {
    int w = threadIdx.x;
    if (w < N_WAVES) {
        float f  = freqs[w];
        float r  = rots[w];
        float c0 = coeffs[2 * w];
        float c1 = coeffs[2 * w + 1];
        float sr, cr;
        sincosf(r, &sr, &cr);
        float amp = sqrtf(c0 * c0 + c1 * c1);
        float phi = atan2f(c1, c0) * 0.15915494309189535f;  // radians -> revs
        wp_out[w] = make_float4(f * cr, f * sr, phi, amp);
    }
}

__global__ __launch_bounds__(BLOCK) void periodic2d_kernel(
    const float* __restrict__ x,        // [N,2]
    const float4* __restrict__ wp_g,    // [W] precomputed {a,b,phi,amp}
    float* __restrict__ out,            // [N]
    int n)
{
    __shared__ float4 wp[N_WAVES];
    const int tid = threadIdx.x;
    if (tid < N_WAVES) wp[tid] = wp_g[tid];
    __syncthreads();

    const float2* __restrict__ X2 = (const float2*)x;
    const int base = blockIdx.x * (BLOCK * PPT) + tid;

    float x0[PPT], x1[PPT], acc[PPT];
#pragma unroll
    for (int k = 0; k < PPT; ++k) {
        int i = base + k * BLOCK;
        x0[k] = 0.f; x1[k] = 0.f; acc[k] = 0.f;
        if (i < n) { float2 v = X2[i]; x0[k] = v.x; x1[k] = v.y; }
    }

#pragma unroll 4
    for (int w = 0; w < N_WAVES; ++w) {
        float4 p = wp[w];
#pragma unroll
        for (int k = 0; k < PPT; ++k) {
            float ph = __builtin_fmaf(p.x, x0[k],
                        __builtin_fmaf(p.y, x1[k], p.z));
            float t  = __builtin_amdgcn_fractf(ph);
            float s  = __builtin_amdgcn_sinf(t);
            acc[k]   = __builtin_fmaf(p.w, s, acc[k]);
        }
    }

#pragma unroll
    for (int k = 0; k < PPT; ++k) {
        int i = base + k * BLOCK;
        if (i < n) out[i] = acc[k];
    }
}

extern "C" void kernel_launch(void* const* d_in, const int* in_sizes, int n_in,
                              void* d_out, int out_size, void* d_ws, size_t ws_size,
                              hipStream_t stream) {
    const float* x      = (const float*)d_in[0];
    const float* freqs  = (const float*)d_in[1];
    const float* rots   = (const float*)d_in[2];
    const float* coeffs = (const float*)d_in[3];
    float* out = (float*)d_out;
    float4* wp = (float4*)d_ws;   // 128 * 16 B = 2 KB scratch

    const int n = out_size;  // 500,000 points
    setup_kernel<<<1, N_WAVES, 0, stream>>>(freqs, rots, coeffs, wp);
    const int grid = (n + BLOCK * PPT - 1) / (BLOCK * PPT);
    periodic2d_kernel<<<grid, BLOCK, 0, stream>>>(x, wp, out, n);
}

// Round 3
// 72.685 us; speedup vs baseline: 1.0094x; 1.0094x over previous
//
#include <hip/hip_runtime.h>
#include <math.h>

#define N_WAVES 128
#define BLOCK 256
#define PPT 2   // points per thread (more waves -> better trans-latency hiding)

// out[n] = sum_w c0*sin(2pi*f*(x0*cos r + x1*sin r)) + c1*cos(...)
//        = sum_w R_w * sin(2pi*(a_w*x0 + b_w*x1) + phi_w)
// a = f*cos r, b = f*sin r, R = hypot(c0,c1), phi = atan2(c1,c0).
// v_sin_f32 computes sin(2pi*x) -> phase kept in revolutions, range-reduce
// with v_fract_f32 (proven: absmax 0.125 vs threshold 0.55).
//
// R3 change: wave params are WAVE-UNIFORM -> read them via the scalar pipe
// (compiler emits s_load_dwordx4 for uniform-indexed __restrict loads) instead
// of LDS broadcast. Removes ~12k cycles/CU of ds_read_b128 pipe pressure,
// the LDS staging, and __syncthreads.

__global__ void setup_kernel(const float* __restrict__ freqs,
                             const float* __restrict__ rots,
                             const float* __restrict__ coeffs,
                             float4* __restrict__ wp_out) {
    int w = threadIdx.x;
    if (w < N_WAVES) {
        float f  = freqs[w];
        float r  = rots[w];
        float c0 = coeffs[2 * w];
        float c1 = coeffs[2 * w + 1];
        float sr, cr;
        sincosf(r, &sr, &cr);              // setup-only: accurate libm path
        float amp = sqrtf(c0 * c0 + c1 * c1);
        float phi = atan2f(c1, c0) * 0.15915494309189535f;  // rad -> revs
        wp_out[w] = make_float4(f * cr, f * sr, phi, amp);
    }
}

__global__ __launch_bounds__(BLOCK) void periodic2d_kernel(
    const float* __restrict__ x,        // [N,2]
    const float4* __restrict__ wp,      // [W] {a,b,phi_rev,amp} (uniform reads)
    float* __restrict__ out,            // [N]
    int n)
{
    const int tid  = threadIdx.x;
    const int ia   = blockIdx.x * (BLOCK * PPT) + tid;
    const int ib   = ia + BLOCK;

    const float2* __restrict__ X2 = (const float2*)x;
    float x0a = 0.f, x1a = 0.f, x0b = 0.f, x1b = 0.f;
    if (ia < n) { float2 v = X2[ia]; x0a = v.x; x1a = v.y; }
    if (ib < n) { float2 v = X2[ib]; x0b = v.x; x1b = v.y; }

    float acca = 0.f, accb = 0.f;
#pragma unroll 8
    for (int w = 0; w < N_WAVES; ++w) {
        // uniform index -> scalar loads (s_load_dwordx4), no LDS, no VMEM
        const float4 p = wp[w];
        float pa = __builtin_fmaf(p.x, x0a, __builtin_fmaf(p.y, x1a, p.z));
        float ta = __builtin_amdgcn_fractf(pa);
        float sa = __builtin_amdgcn_sinf(ta);
        acca = __builtin_fmaf(p.w, sa, acca);

        float pb = __builtin_fmaf(p.x, x0b, __builtin_fmaf(p.y, x1b, p.z));
        float tb = __builtin_amdgcn_fractf(pb);
        float sb = __builtin_amdgcn_sinf(tb);
        accb = __builtin_fmaf(p.w, sb, accb);
    }

    if (ia < n) out[ia] = acca;
    if (ib < n) out[ib] = accb;
}

extern "C" void kernel_launch(void* const* d_in, const int* in_sizes, int n_in,
                              void* d_out, int out_size, void* d_ws, size_t ws_size,
                              hipStream_t stream) {
    const float* x      = (const float*)d_in[0];
    const float* freqs  = (const float*)d_in[1];
    const float* rots   = (const float*)d_in[2];
    const float* coeffs = (const float*)d_in[3];
    float* out = (float*)d_out;
    float4* wp = (float4*)d_ws;   // 128 * 16 B = 2 KB scratch

    const int n = out_size;  // 500,000 points
    setup_kernel<<<1, N_WAVES, 0, stream>>>(freqs, rots, coeffs, wp);
    const int grid = (n + BLOCK * PPT - 1) / (BLOCK * PPT);  // 977 blocks
    periodic2d_kernel<<<grid, BLOCK, 0, stream>>>(x, wp, out, n);
}